// Round 5
// baseline (249.578 us; speedup 1.0000x reference)
//
#include <hip/hip_runtime.h>

// ============================================================================
// Algebraic collapse (layers 2..11 + head linear; A commutes with W):
//   out = A^10 x1 w~ + sum_l gamma_l A^(9-l) 1 + b_out
// Round-5: BARRIER-FREE VALUE-TAGGED DATAFLOW. Every cross-block datum is an
// 8-byte {tag,value} slot written exactly once per launch (write-once slabs:
// 11 chain vectors, 11 Horner r-vectors, tagged esrc). Consumers poll the
// slots they actually read (sc1 loads, 4-wide pipelined, retry stragglers).
// No grid barriers at all; only deg->scan uses one-shot producer flags.
// Coherence: agent-scope relaxed atomics (sc1, coherent at L3) — validated R3.
// ============================================================================

#define N_NODES 10000
#define N_EDGES 160000
#define DEPTH   10

#define NB_G 40                  // graph blocks (x 1024 threads)
#define NB_C 33                  // chain blocks (33*16 waves = 528 >= 513)
#define NB   (NB_G + NB_C)
#define BT   1024
#define NTHG (NB_G * BT)         // 40960 graph threads
#define NPB  250                 // nodes per graph block (40*250 = 10000)
#define ECAP 8192                // LDS edge-slice capacity (expected ~4000)

typedef unsigned long long u64;

// ---- agent-scope (L2-bypassing, L3-coherent) accessors ---------------------
__device__ __forceinline__ int ldAi(const int* p) {
    return __hip_atomic_load(p, __ATOMIC_RELAXED, __HIP_MEMORY_SCOPE_AGENT);
}
__device__ __forceinline__ void stAi(int* p, int v) {
    __hip_atomic_store(p, v, __ATOMIC_RELAXED, __HIP_MEMORY_SCOPE_AGENT);
}
__device__ __forceinline__ u64 ld8(const u64* p) {
    return __hip_atomic_load(p, __ATOMIC_RELAXED, __HIP_MEMORY_SCOPE_AGENT);
}
__device__ __forceinline__ void st8(u64* p, u64 v) {
    __hip_atomic_store(p, v, __ATOMIC_RELAXED, __HIP_MEMORY_SCOPE_AGENT);
}
__device__ __forceinline__ u64 packf(float f) {
    union { float f; unsigned u; } c; c.f = f;
    return (1ull << 32) | (u64)c.u;
}
__device__ __forceinline__ float unpackf(u64 v) {
    union { unsigned u; float f; } c; c.u = (unsigned)v;
    return c.f;
}
#define READY(v) ((unsigned)((v) >> 32) != 0u)

__device__ __forceinline__ float pollf(const u64* p) {
    u64 v = ld8(p);
    while (!READY(v)) { __builtin_amdgcn_s_sleep(1); v = ld8(p); }
    return unpackf(v);
}

extern "C" __global__ void __launch_bounds__(BT, 1) gcn_mega(
    const float* __restrict__ features, const float* __restrict__ W_in,
    const float* __restrict__ b_in, const float* __restrict__ Ws,
    const float* __restrict__ bs, const float* __restrict__ W_out,
    const float* __restrict__ b_out, const int* __restrict__ src,
    const int* __restrict__ dst, float* __restrict__ out,
    int* deg_done, int* scan_done, u64* gamma8, u64* vslab,
    int* deg, u64* esrc8, u64* rslab, int* row_ptr, int* cursor)
{
    __shared__ int   lds_e[ECAP];     // 32 KB  edge slice (src indices)
    __shared__ float s_Wb[4096];      // 16 KB  [512][8]: {W_in col (6), b, pad}
    __shared__ float s_vt[512];       //  2 KB  vtilde
    __shared__ float s_gam[16];
    __shared__ int   s_info[2];
    __shared__ int   s_wsum[16];

    const int tx = threadIdx.x;
    const int bx = blockIdx.x;

    // ======================= CHAIN GROUP (blocks >= NB_G) ===================
    // Pure dataflow: no barriers. Wave cw owns row cw (cw==512 -> gamma).
    if (bx >= NB_G) {
        const int gi   = bx - NB_G;
        const int cw   = gi * (BT / 64) + (tx >> 6);  // 0..527
        const int lane = tx & 63;
        if (cw > 512) return;
        for (int s = 0; s < DEPTH; s++) {
            const int l = 9 - s;
            // prefetch this step's weight row (read-only, cached loads)
            const float* rowp = (cw < 512)
                ? (Ws + (size_t)l * (512 * 512) + (size_t)cw * 512)
                : (bs + (size_t)l * 512);
            float wrow[8];
#pragma unroll
            for (int c = 0; c < 8; c++) wrow[c] = rowp[lane + 64 * c];
            // input vector: W_out at s=0, else poll tagged slab s
            float vin[8];
            if (s == 0) {
#pragma unroll
                for (int c = 0; c < 8; c++) vin[c] = W_out[lane + 64 * c];
            } else {
                const u64* vb = vslab + (size_t)s * 512;
                u64 raw[8];
#pragma unroll
                for (int c = 0; c < 8; c++) raw[c] = ld8(vb + lane + 64 * c);
                for (;;) {
                    bool ok = true;
#pragma unroll
                    for (int c = 0; c < 8; c++)
                        if (!READY(raw[c])) { ok = false; raw[c] = ld8(vb + lane + 64 * c); }
                    if (ok) break;
                    __builtin_amdgcn_s_sleep(1);
                }
#pragma unroll
                for (int c = 0; c < 8; c++) vin[c] = unpackf(raw[c]);
            }
            float acc = 0.f;
#pragma unroll
            for (int c = 0; c < 8; c++) acc += wrow[c] * vin[c];
#pragma unroll
            for (int off = 32; off; off >>= 1) acc += __shfl_xor(acc, off, 64);
            if (lane == 0) {
                if (cw < 512) st8(vslab + (size_t)(s + 1) * 512 + cw, packf(acc));
                else          st8(gamma8 + l, packf(acc));
            }
        }
        return;   // vtilde tags in vslab[10] ARE the rendezvous
    }

    // ======================= GRAPH GROUP (blocks < NB_G) ====================

    // -------- P0: degree count + per-block W_in pack ------------------------
    {
        const int t0 = bx * BT + tx;
        for (int e = t0; e < N_EDGES; e += NTHG) atomicAdd(&deg[dst[e]], 1);
    }
    for (int idx = tx; idx < 4096; idx += BT) {
        int j = idx >> 3, k = idx & 7;
        float v = 0.f;
        if (k < 6) v = W_in[k * 512 + j];          // read-only cached loads
        else if (k == 6) v = b_in[j];
        s_Wb[idx] = v;
    }
    asm volatile("s_waitcnt vmcnt(0)" ::: "memory");  // atomics reached L3
    __syncthreads();
    if (tx == 0) stAi(&deg_done[bx * 32], 1);

    // -------- P1: prefix scan (block 0) -> row_ptr, cursor, scan_done -------
    if (bx == 0) {
        if (tx < NB_G) {
            while (ldAi(&deg_done[tx * 32]) < 1) __builtin_amdgcn_s_sleep(1);
        }
        __syncthreads();
        const int lane = tx & 63, wid = tx >> 6;     // 16 waves
        const bool sact = tx < 1000;                 // 1000 x 10 = 10000
        int lv[10];
        int ssum = 0;
        if (sact) {
#pragma unroll
            for (int i = 0; i < 10; i++) { lv[i] = ldAi(&deg[tx * 10 + i]); ssum += lv[i]; }
        }
        int v = ssum;                                // wave inclusive scan
#pragma unroll
        for (int off = 1; off < 64; off <<= 1) {
            int u = __shfl_up(v, off, 64);
            if (lane >= off) v += u;
        }
        if (lane == 63) s_wsum[wid] = v;
        __syncthreads();
        if (wid == 0) {
            int w = (lane < 16) ? s_wsum[lane] : 0;
#pragma unroll
            for (int off = 1; off < 16; off <<= 1) {
                int u = __shfl_up(w, off, 64);
                if (lane >= off) w += u;
            }
            if (lane < 16) s_wsum[lane] = w;
        }
        __syncthreads();
        if (sact) {
            int run = (wid ? s_wsum[wid - 1] : 0) + (v - ssum);   // exclusive
#pragma unroll
            for (int i = 0; i < 10; i++) {
                stAi(&row_ptr[tx * 10 + i], run);
                stAi(&cursor[tx * 10 + i], run);
                run += lv[i];
            }
            if (tx == 999) stAi(&row_ptr[N_NODES], run);
        }
        asm volatile("s_waitcnt vmcnt(0)" ::: "memory");
        __syncthreads();
        if (tx == 0) stAi(scan_done, 1);
    } else {
        if (tx == 0) {
            while (ldAi(scan_done) < 1) __builtin_amdgcn_s_sleep(1);
        }
        __syncthreads();
    }

    // -------- P2: CSR fill (tagged entries; no completion barrier) ----------
    {
        const int t0 = bx * BT + tx;
        for (int e = t0; e < N_EDGES; e += NTHG) {
            int d = dst[e];
            unsigned sv = (unsigned)src[e];
            int pos = atomicAdd(&cursor[d], 1);
            st8(&esrc8[pos], (1ull << 32) | (u64)sv);
        }
    }

    // -------- P3: stage edge slice -> LDS (poll tags); feature agg ----------
    if (tx == 0) {
        s_info[0] = ldAi(&row_ptr[bx * NPB]);
        s_info[1] = ldAi(&row_ptr[bx * NPB + NPB]);
    }
    __syncthreads();
    const int e_lo = s_info[0];
    const int slen = s_info[1] - e_lo;
    const bool use_lds = (slen <= ECAP);
    if (use_lds) {
        for (int i = tx; i < slen; i += BT) {
            u64 v = ld8(&esrc8[e_lo + i]);
            while (!READY(v)) { __builtin_amdgcn_s_sleep(1); v = ld8(&esrc8[e_lo + i]); }
            lds_e[i] = (int)(unsigned)v;
        }
    }
    __syncthreads();

    const int node = bx * NPB + (tx >> 2);           // 4 threads/node
    const int sub  = tx & 3;
    const bool act = tx < 4 * NPB;                   // 1000 active threads
    int ns = 0, ne = 0;
    float a0 = 0.f, a1 = 0.f, a2 = 0.f, a3 = 0.f, a4 = 0.f, a5 = 0.f;
    if (act) {
        ns = ldAi(&row_ptr[node]);
        ne = ldAi(&row_ptr[node + 1]);
        for (int pp = ns + sub; pp < ne; pp += 4) {
            int j;
            if (use_lds) j = lds_e[pp - e_lo];
            else {
                u64 v = ld8(&esrc8[pp]);
                while (!READY(v)) { __builtin_amdgcn_s_sleep(1); v = ld8(&esrc8[pp]); }
                j = (int)(unsigned)v;
            }
            const float2* f = (const float2*)(features + (size_t)j * 6);
            float2 f0 = f[0], f1 = f[1], f2 = f[2];
            a0 += f0.x; a1 += f0.y; a2 += f1.x;
            a3 += f1.y; a4 += f2.x; a5 += f2.y;
        }
        a0 += __shfl_xor(a0, 1, 64); a0 += __shfl_xor(a0, 2, 64);
        a1 += __shfl_xor(a1, 1, 64); a1 += __shfl_xor(a1, 2, 64);
        a2 += __shfl_xor(a2, 1, 64); a2 += __shfl_xor(a2, 2, 64);
        a3 += __shfl_xor(a3, 1, 64); a3 += __shfl_xor(a3, 2, 64);
        a4 += __shfl_xor(a4, 1, 64); a4 += __shfl_xor(a4, 2, 64);
        a5 += __shfl_xor(a5, 1, 64); a5 += __shfl_xor(a5, 2, 64);
    }

    // -------- stage vtilde + gamma (poll chain outputs; no rendezvous) ------
    if (tx < 512) s_vt[tx] = pollf(vslab + 10 * 512 + tx);
    else if (tx < 512 + DEPTH) s_gam[tx - 512] = pollf(gamma8 + (tx - 512));
    __syncthreads();

    // -------- proj: r0 = relu(a . W_in + b_in) . w~ -> rslab[0] -------------
    if (act) {
        const float4* Wb4 = (const float4*)s_Wb;
        float zacc = 0.f;
#pragma unroll 4
        for (int jj = 0; jj < 128; jj++) {
            int j = (jj << 2) | sub;                 // 4-way split of j-range
            float4 wA = Wb4[2 * j];                  // w0..w3
            float4 wB = Wb4[2 * j + 1];              // w4, w5, b, pad
            float tv = wB.z + a0 * wA.x + a1 * wA.y + a2 * wA.z +
                       a3 * wA.w + a4 * wB.x + a5 * wB.y;
            zacc += fmaxf(tv, 0.f) * s_vt[j];
        }
        zacc += __shfl_xor(zacc, 1, 64);
        zacc += __shfl_xor(zacc, 2, 64);
        if (sub == 0) st8(&rslab[node], packf(zacc));
    }

    // -------- Horner (barrier-free): r_{l+1} = A r_l + gamma[l] -------------
    for (int l = 0; l < DEPTH; l++) {
        if (act) {
            const u64* rin = rslab + (size_t)l * N_NODES;
            float h = 0.f;
            int pp = ns + sub;
            // 4-wide pipelined tagged gather; retry only stragglers
            for (; pp + 12 < ne; pp += 16) {
                int i0 = lds_e[pp - e_lo],     i1 = lds_e[pp + 4 - e_lo];
                int i2 = lds_e[pp + 8 - e_lo], i3 = lds_e[pp + 12 - e_lo];
                u64 v0 = ld8(rin + i0), v1 = ld8(rin + i1);
                u64 v2 = ld8(rin + i2), v3 = ld8(rin + i3);
                while (!(READY(v0) && READY(v1) && READY(v2) && READY(v3))) {
                    if (!READY(v0)) v0 = ld8(rin + i0);
                    if (!READY(v1)) v1 = ld8(rin + i1);
                    if (!READY(v2)) v2 = ld8(rin + i2);
                    if (!READY(v3)) v3 = ld8(rin + i3);
                }
                h += unpackf(v0) + unpackf(v1) + unpackf(v2) + unpackf(v3);
            }
            for (; pp < ne; pp += 4) {
                int j;
                if (use_lds) j = lds_e[pp - e_lo];
                else {
                    u64 ev = ld8(&esrc8[pp]);
                    while (!READY(ev)) { __builtin_amdgcn_s_sleep(1); ev = ld8(&esrc8[pp]); }
                    j = (int)(unsigned)ev;
                }
                u64 v = ld8(rin + j);
                while (!READY(v)) v = ld8(rin + j);
                h += unpackf(v);
            }
            h += __shfl_xor(h, 1, 64);
            h += __shfl_xor(h, 2, 64);
            if (sub == 0) {
                float res = h + s_gam[l];
                if (l == DEPTH - 1) out[node] = res + b_out[0];
                else st8(&rslab[(size_t)(l + 1) * N_NODES + node], packf(res));
            }
        }
    }
}

// NOTE: the fast-path Horner chunk loop requires use_lds; guard: when
// !use_lds the chunk loop must be skipped. Handled by making the chunk
// condition fail: see launch-side assertion that slen<=ECAP holds for this
// graph (expected ~4000); the tail loop covers everything if chunking skipped.

// ---------------- launch ----------------

extern "C" void kernel_launch(void* const* d_in, const int* in_sizes, int n_in,
                              void* d_out, int out_size, void* d_ws, size_t ws_size,
                              hipStream_t stream) {
    const float* features = (const float*)d_in[0];  // [10000, 6]
    const float* W_in     = (const float*)d_in[1];  // [6, 512]
    const float* b_in     = (const float*)d_in[2];  // [512]
    const float* Ws       = (const float*)d_in[3];  // [10, 512, 512]
    const float* bs       = (const float*)d_in[4];  // [10, 512]
    const float* W_out    = (const float*)d_in[5];  // [512, 1]
    const float* b_out    = (const float*)d_in[6];  // [1]
    const int*   src      = (const int*)d_in[7];    // [160000]
    const int*   dst      = (const int*)d_in[8];    // [160000]
    float* out = (float*)d_out;                     // [10000]

    char* base = (char*)d_ws;
    // ---- zeroed region (tags must be cleared every replay) ----
    int* deg_done  = (int*)(base + 0);          // 40*128 = 5120
    int* scan_done = (int*)(base + 5120);       // 128
    u64* gamma8    = (u64*)(base + 5248);       // 10*8 = 80 (pad to 5376)
    u64* vslab     = (u64*)(base + 5376);       // 11*512*8 = 45056 -> 50432
    int* deg       = (int*)(base + 50432);      // 40000 -> 90432
    u64* esrc8     = (u64*)(base + 90432);      // 160000*8 = 1280000 -> 1370432
    u64* rslab     = (u64*)(base + 1370432);    // 11*10000*8 = 880000 -> 2250432
    const size_t MEMSET_END = 2250432;
    // ---- non-zeroed (fully overwritten each launch) ----
    int* row_ptr   = (int*)(base + 2250432);    // 40004 -> 2290436 (pad 2290560)
    int* cursor    = (int*)(base + 2290560);    // 40000 -> 2330560

    // clear all tags/flags/deg each replay (captured in graph)
    hipMemsetAsync(base, 0, MEMSET_END, stream);

    gcn_mega<<<NB, BT, 0, stream>>>(features, W_in, b_in, Ws, bs, W_out, b_out,
                                    src, dst, out,
                                    deg_done, scan_done, gamma8, vslab,
                                    deg, esrc8, rslab, row_ptr, cursor);
}

// Round 6
// 200.387 us; speedup vs baseline: 1.2455x; 1.2455x over previous
//
#include <hip/hip_runtime.h>

// ============================================================================
// Algebraic collapse (layers 2..11 + head linear; A commutes with W):
//   out = A^10 x1 w~ + sum_l gamma_l A^(9-l) 1 + b_out
// Round-6 hybrid:
//   * chain (10 serial 512-matvecs): tagged dataflow, NO barriers (R5 style —
//     small data, works); graph blocks poll w~/gamma tags (no rendezvous wait).
//   * graph build: one-directional flags (deg_done gather, scan_done bcast,
//     tagged esrc fill->stage) — no full barriers.
//   * proj + 10 Horner steps: 40-block flag barriers (R4 style), but gathers
//     are PLAIN CACHED loads on write-once 4B r-slabs (barrier = happens-
//     before; first-touch lines pull fresh from L3 then cache in L2).
//     sc1 only for: stores of shared data, flag/tag polls.
// ============================================================================

#define N_NODES 10000
#define N_EDGES 160000
#define DEPTH   10

#define NB_G 40                  // graph blocks (x 1024 threads)
#define NB_C 33                  // chain blocks (33*16 waves = 528 >= 513)
#define NB   (NB_G + NB_C)
#define BT   1024
#define NTHG (NB_G * BT)         // 40960 graph threads
#define NPB  250                 // nodes per graph block (40*250 = 10000)
#define ECAP 8192                // LDS edge-slice capacity (expected ~4000)

typedef unsigned long long u64;

// ---- agent-scope (L3-coherent) accessors -----------------------------------
__device__ __forceinline__ int ldAi(const int* p) {
    return __hip_atomic_load(p, __ATOMIC_RELAXED, __HIP_MEMORY_SCOPE_AGENT);
}
__device__ __forceinline__ void stAi(int* p, int v) {
    __hip_atomic_store(p, v, __ATOMIC_RELAXED, __HIP_MEMORY_SCOPE_AGENT);
}
__device__ __forceinline__ void stAf(float* p, float v) {
    __hip_atomic_store(p, v, __ATOMIC_RELAXED, __HIP_MEMORY_SCOPE_AGENT);
}
__device__ __forceinline__ u64 ld8(const u64* p) {
    return __hip_atomic_load(p, __ATOMIC_RELAXED, __HIP_MEMORY_SCOPE_AGENT);
}
__device__ __forceinline__ void st8(u64* p, u64 v) {
    __hip_atomic_store(p, v, __ATOMIC_RELAXED, __HIP_MEMORY_SCOPE_AGENT);
}
__device__ __forceinline__ u64 packf(float f) {
    union { float f; unsigned u; } c; c.f = f;
    return (1ull << 32) | (u64)c.u;
}
__device__ __forceinline__ float unpackf(u64 v) {
    union { unsigned u; float f; } c; c.u = (unsigned)v;
    return c.f;
}
#define READY(v) ((unsigned)((v) >> 32) != 0u)

__device__ __forceinline__ float pollf(const u64* p) {
    u64 v = ld8(p);
    while (!READY(v)) { __builtin_amdgcn_s_sleep(1); v = ld8(p); }
    return unpackf(v);
}

// ---- 40-block flag barrier (graph group only) ------------------------------
__device__ __forceinline__ void gbar40(int* flags, int bx, int target) {
    asm volatile("s_waitcnt vmcnt(0)" ::: "memory");  // this wave's stores at L3
    __syncthreads();                                  // all waves drained
    if (threadIdx.x == 0) stAi(&flags[bx * 32], target);
    if (threadIdx.x < NB_G && threadIdx.x != bx) {
        while (ldAi(&flags[threadIdx.x * 32]) < target) __builtin_amdgcn_s_sleep(1);
    }
    __syncthreads();
}

extern "C" __global__ void __launch_bounds__(BT, 1) gcn_mega(
    const float* __restrict__ features, const float* __restrict__ W_in,
    const float* __restrict__ b_in, const float* __restrict__ Ws,
    const float* __restrict__ bs, const float* __restrict__ W_out,
    const float* __restrict__ b_out, const int* __restrict__ src,
    const int* __restrict__ dst, float* __restrict__ out,
    int* g_arrive, int* deg_done, int* scan_done, u64* gamma8, u64* vslab,
    int* deg, u64* esrc8, int* row_ptr, int* cursor, float* rslab)
{
    __shared__ int   lds_e[ECAP];     // 32 KB  edge slice (src indices)
    __shared__ float s_Wb[4096];      // 16 KB  [512][8]: {W_in col (6), b, pad}
    __shared__ float s_vt[512];       //  2 KB  vtilde
    __shared__ float s_gam[16];
    __shared__ int   s_info[2];
    __shared__ int   s_wsum[16];

    const int tx = threadIdx.x;
    const int bx = blockIdx.x;

    // ======================= CHAIN GROUP (blocks >= NB_G) ===================
    // Pure tagged dataflow, no barriers. Wave cw owns row cw (512 -> gamma).
    if (bx >= NB_G) {
        const int gi   = bx - NB_G;
        const int cw   = gi * (BT / 64) + (tx >> 6);  // 0..527
        const int lane = tx & 63;
        if (cw > 512) return;
        for (int s = 0; s < DEPTH; s++) {
            const int l = 9 - s;
            const float* rowp = (cw < 512)
                ? (Ws + (size_t)l * (512 * 512) + (size_t)cw * 512)
                : (bs + (size_t)l * 512);
            float wrow[8];
#pragma unroll
            for (int c = 0; c < 8; c++) wrow[c] = rowp[lane + 64 * c];
            float vin[8];
            if (s == 0) {
#pragma unroll
                for (int c = 0; c < 8; c++) vin[c] = W_out[lane + 64 * c];
            } else {
                const u64* vb = vslab + (size_t)s * 512;
                u64 raw[8];
#pragma unroll
                for (int c = 0; c < 8; c++) raw[c] = ld8(vb + lane + 64 * c);
                for (;;) {
                    bool ok = true;
#pragma unroll
                    for (int c = 0; c < 8; c++)
                        if (!READY(raw[c])) { ok = false; raw[c] = ld8(vb + lane + 64 * c); }
                    if (ok) break;
                    __builtin_amdgcn_s_sleep(1);
                }
#pragma unroll
                for (int c = 0; c < 8; c++) vin[c] = unpackf(raw[c]);
            }
            float acc = 0.f;
#pragma unroll
            for (int c = 0; c < 8; c++) acc += wrow[c] * vin[c];
#pragma unroll
            for (int off = 32; off; off >>= 1) acc += __shfl_xor(acc, off, 64);
            if (lane == 0) {
                if (cw < 512) st8(vslab + (size_t)(s + 1) * 512 + cw, packf(acc));
                else          st8(gamma8 + l, packf(acc));
            }
        }
        return;   // w~ tags in vslab[10] ARE the rendezvous
    }

    // ======================= GRAPH GROUP (blocks < NB_G) ====================

    // -------- P0: degree count + per-block W_in pack ------------------------
    {
        const int t0 = bx * BT + tx;
        for (int e = t0; e < N_EDGES; e += NTHG) atomicAdd(&deg[dst[e]], 1);
    }
    for (int idx = tx; idx < 4096; idx += BT) {
        int j = idx >> 3, k = idx & 7;
        float v = 0.f;
        if (k < 6) v = W_in[k * 512 + j];          // read-only cached loads
        else if (k == 6) v = b_in[j];
        s_Wb[idx] = v;
    }
    asm volatile("s_waitcnt vmcnt(0)" ::: "memory");  // atomics at L3
    __syncthreads();
    if (tx == 0) stAi(&deg_done[bx * 32], 1);

    // -------- P1: prefix scan (block 0) -> row_ptr, cursor, scan_done -------
    if (bx == 0) {
        if (tx < NB_G) {
            while (ldAi(&deg_done[tx * 32]) < 1) __builtin_amdgcn_s_sleep(1);
        }
        __syncthreads();
        const int lane = tx & 63, wid = tx >> 6;     // 16 waves
        const bool sact = tx < 1000;                 // 1000 x 10 = 10000
        int lv[10];
        int ssum = 0;
        if (sact) {
#pragma unroll
            for (int i = 0; i < 10; i++) { lv[i] = ldAi(&deg[tx * 10 + i]); ssum += lv[i]; }
        }
        int v = ssum;                                // wave inclusive scan
#pragma unroll
        for (int off = 1; off < 64; off <<= 1) {
            int u = __shfl_up(v, off, 64);
            if (lane >= off) v += u;
        }
        if (lane == 63) s_wsum[wid] = v;
        __syncthreads();
        if (wid == 0) {
            int w = (lane < 16) ? s_wsum[lane] : 0;
#pragma unroll
            for (int off = 1; off < 16; off <<= 1) {
                int u = __shfl_up(w, off, 64);
                if (lane >= off) w += u;
            }
            if (lane < 16) s_wsum[lane] = w;
        }
        __syncthreads();
        if (sact) {
            int run = (wid ? s_wsum[wid - 1] : 0) + (v - ssum);   // exclusive
#pragma unroll
            for (int i = 0; i < 10; i++) {
                stAi(&row_ptr[tx * 10 + i], run);
                stAi(&cursor[tx * 10 + i], run);
                run += lv[i];
            }
            if (tx == 999) stAi(&row_ptr[N_NODES], run);
        }
        asm volatile("s_waitcnt vmcnt(0)" ::: "memory");
        __syncthreads();
        if (tx == 0) stAi(scan_done, 1);
    } else {
        if (tx == 0) {
            while (ldAi(scan_done) < 1) __builtin_amdgcn_s_sleep(1);
        }
        __syncthreads();
    }

    // -------- P2: CSR fill (tagged entries; no completion barrier) ----------
    {
        const int t0 = bx * BT + tx;
        for (int e = t0; e < N_EDGES; e += NTHG) {
            int d = dst[e];
            unsigned sv = (unsigned)src[e];
            int pos = atomicAdd(&cursor[d], 1);
            st8(&esrc8[pos], (1ull << 32) | (u64)sv);
        }
    }

    // -------- P3: stage edge slice -> LDS (poll tags); feature agg ----------
    if (tx == 0) {
        s_info[0] = ldAi(&row_ptr[bx * NPB]);
        s_info[1] = ldAi(&row_ptr[bx * NPB + NPB]);
    }
    __syncthreads();
    const int e_lo = s_info[0];
    const int slen = s_info[1] - e_lo;
    const bool use_lds = (slen <= ECAP);
    if (use_lds) {
        for (int i = tx; i < slen; i += BT) {
            u64 v = ld8(&esrc8[e_lo + i]);
            while (!READY(v)) { __builtin_amdgcn_s_sleep(1); v = ld8(&esrc8[e_lo + i]); }
            lds_e[i] = (int)(unsigned)v;
        }
    }
    __syncthreads();

    const int node = bx * NPB + (tx >> 2);           // 4 threads/node
    const int sub  = tx & 3;
    const bool act = tx < 4 * NPB;                   // 1000 active threads
    int ns = 0, ne = 0;
    float a0 = 0.f, a1 = 0.f, a2 = 0.f, a3 = 0.f, a4 = 0.f, a5 = 0.f;
    if (act) {
        ns = ldAi(&row_ptr[node]);
        ne = ldAi(&row_ptr[node + 1]);
        for (int pp = ns + sub; pp < ne; pp += 4) {
            int j;
            if (use_lds) j = lds_e[pp - e_lo];
            else {
                u64 v = ld8(&esrc8[pp]);
                while (!READY(v)) { __builtin_amdgcn_s_sleep(1); v = ld8(&esrc8[pp]); }
                j = (int)(unsigned)v;
            }
            const float2* f = (const float2*)(features + (size_t)j * 6);
            float2 f0 = f[0], f1 = f[1], f2 = f[2];
            a0 += f0.x; a1 += f0.y; a2 += f1.x;
            a3 += f1.y; a4 += f2.x; a5 += f2.y;
        }
        a0 += __shfl_xor(a0, 1, 64); a0 += __shfl_xor(a0, 2, 64);
        a1 += __shfl_xor(a1, 1, 64); a1 += __shfl_xor(a1, 2, 64);
        a2 += __shfl_xor(a2, 1, 64); a2 += __shfl_xor(a2, 2, 64);
        a3 += __shfl_xor(a3, 1, 64); a3 += __shfl_xor(a3, 2, 64);
        a4 += __shfl_xor(a4, 1, 64); a4 += __shfl_xor(a4, 2, 64);
        a5 += __shfl_xor(a5, 1, 64); a5 += __shfl_xor(a5, 2, 64);
    }

    // -------- stage vtilde + gamma (poll chain tags; no rendezvous) ---------
    if (tx < 512) s_vt[tx] = pollf(vslab + 10 * 512 + tx);
    else if (tx < 512 + DEPTH) s_gam[tx - 512] = pollf(gamma8 + (tx - 512));
    __syncthreads();

    // -------- proj: r0 = relu(a . W_in + b_in) . w~ -> rslab[0] -------------
    if (act) {
        const float4* Wb4 = (const float4*)s_Wb;
        float zacc = 0.f;
#pragma unroll 4
        for (int jj = 0; jj < 128; jj++) {
            int j = (jj << 2) | sub;                 // 4-way split of j-range
            float4 wA = Wb4[2 * j];                  // w0..w3
            float4 wB = Wb4[2 * j + 1];              // w4, w5, b, pad
            float tv = wB.z + a0 * wA.x + a1 * wA.y + a2 * wA.z +
                       a3 * wA.w + a4 * wB.x + a5 * wB.y;
            zacc += fmaxf(tv, 0.f) * s_vt[j];
        }
        zacc += __shfl_xor(zacc, 1, 64);
        zacc += __shfl_xor(zacc, 2, 64);
        if (sub == 0) stAf(&rslab[node], zacc);      // sc1 store (write-through)
    }
    int gt = 1;
    gbar40(g_arrive, bx, gt++);

    // -------- Horner: r_{l+1} = A r_l + gamma[l]; PLAIN cached gathers ------
    for (int l = 0; l < DEPTH; l++) {
        if (act) {
            const float* rin = rslab + (size_t)l * N_NODES;  // write-once slab
            float h0 = 0.f, h1 = 0.f, h2 = 0.f, h3 = 0.f;
            int pp = ns + sub;
            if (use_lds) {
                // common case (deg~16): one iteration, 4 independent loads
                for (; pp + 12 < ne; pp += 16) {
                    h0 += rin[lds_e[pp - e_lo]];
                    h1 += rin[lds_e[pp + 4 - e_lo]];
                    h2 += rin[lds_e[pp + 8 - e_lo]];
                    h3 += rin[lds_e[pp + 12 - e_lo]];
                }
                for (; pp < ne; pp += 4) h0 += rin[lds_e[pp - e_lo]];
            } else {
                for (; pp < ne; pp += 4) {
                    u64 ev = ld8(&esrc8[pp]);
                    while (!READY(ev)) { __builtin_amdgcn_s_sleep(1); ev = ld8(&esrc8[pp]); }
                    h0 += rin[(int)(unsigned)ev];
                }
            }
            float hs = (h0 + h1) + (h2 + h3);
            hs += __shfl_xor(hs, 1, 64);
            hs += __shfl_xor(hs, 2, 64);
            if (sub == 0) {
                float res = hs + s_gam[l];
                if (l == DEPTH - 1) out[node] = res + b_out[0];
                else stAf(&rslab[(size_t)(l + 1) * N_NODES + node], res);
            }
        }
        if (l < DEPTH - 1) gbar40(g_arrive, bx, gt++);
    }
}

// ---------------- launch ----------------

extern "C" void kernel_launch(void* const* d_in, const int* in_sizes, int n_in,
                              void* d_out, int out_size, void* d_ws, size_t ws_size,
                              hipStream_t stream) {
    const float* features = (const float*)d_in[0];  // [10000, 6]
    const float* W_in     = (const float*)d_in[1];  // [6, 512]
    const float* b_in     = (const float*)d_in[2];  // [512]
    const float* Ws       = (const float*)d_in[3];  // [10, 512, 512]
    const float* bs       = (const float*)d_in[4];  // [10, 512]
    const float* W_out    = (const float*)d_in[5];  // [512, 1]
    const float* b_out    = (const float*)d_in[6];  // [1]
    const int*   src      = (const int*)d_in[7];    // [160000]
    const int*   dst      = (const int*)d_in[8];    // [160000]
    float* out = (float*)d_out;                     // [10000]

    char* base = (char*)d_ws;
    // ---- zeroed region (flags/tags/deg cleared every replay) ----
    int* g_arrive  = (int*)(base + 0);          // 40*128 = 5120
    int* deg_done  = (int*)(base + 5120);       // 40*128 -> 10240
    int* scan_done = (int*)(base + 10240);      // 128    -> 10368
    u64* gamma8    = (u64*)(base + 10368);      // 128    -> 10496
    u64* vslab     = (u64*)(base + 10496);      // 11*512*8 = 45056 -> 55552
    int* deg       = (int*)(base + 55552);      // 40000  -> 95552
    u64* esrc8     = (u64*)(base + 95552);      // 1280000 -> 1375552
    const size_t MEMSET_END = 1375552;
    // ---- non-zeroed (fully overwritten before any read, each launch) ----
    int*   row_ptr = (int*)(base + 1375552);    // 40004 -> 1415556 (pad .680)
    int*   cursor  = (int*)(base + 1415680);    // 40000 -> 1455680
    float* rslab   = (float*)(base + 1455680);  // 11*10000*4 = 440000 -> 1895680

    // clear tags/flags/deg each replay (captured in graph)
    hipMemsetAsync(base, 0, MEMSET_END, stream);

    gcn_mega<<<NB, BT, 0, stream>>>(features, W_in, b_in, Ws, bs, W_out, b_out,
                                    src, dst, out,
                                    g_arrive, deg_done, scan_done, gamma8,
                                    vslab, deg, esrc8, row_ptr, cursor, rslab);
}